// Round 2
// baseline (351.883 us; speedup 1.0000x reference)
//
#include <hip/hip_runtime.h>

// ---------------- problem constants ----------------
#define BM   8192      // B*M = 2*4096 points
#define NN1  16384
#define NN2  8192
#define NN3  4096

// ---------------- workspace layout (float/int32 indices) ----------------
#define OFF_LRXYZ 0            // 8192 float4
#define OFF_XYZ1  32768        // 2*16384 float4
#define OFF_XYZ2  163840       // 2*8192  float4
#define OFF_XYZ3  229376       // 2*4096  float4
#define OFF_F1    262144       // 2*16384*32 f32
#define OFF_F2    1310720      // 2*8192*32
#define OFF_F3    1835008      // 2*4096*32
#define OFF_ACC1  2097152      // 8192*32 (int bits of f32, >=0)
#define OFF_ACC2  2359296
#define OFF_ACC3  2621440
#define OFF_CNT1  2883584      // 8192 int
#define OFF_CNT2  2891776
#define OFF_CNT3  2899968
#define OFF_WP    2908160      // 160*64 BN-folded w_out
#define OFF_SHIFT 2918400      // 64
#define WS_FLOATS 2918464      // ~11.7 MB

#define ZERO_BASE OFF_ACC1
#define ZERO_LEN  811008       // acc1..cnt3 contiguous

// ---------------- kernel A: precompute xyz, F, w', zero acc ----------------
__global__ __launch_bounds__(256) void kprep(
    const int* __restrict__ lr_idx, const int* __restrict__ h1i,
    const int* __restrict__ h2i, const int* __restrict__ h3i,
    const float* __restrict__ f1, const float* __restrict__ f2, const float* __restrict__ f3,
    const float* __restrict__ w14, const float* __restrict__ b14,
    const float* __restrict__ w24, const float* __restrict__ b24,
    const float* __restrict__ w34, const float* __restrict__ b34,
    const float* __restrict__ wout, const float* __restrict__ gam,
    const float* __restrict__ bet, const float* __restrict__ mean,
    const float* __restrict__ var, float* __restrict__ ws)
{
    int e = blockIdx.x * 256 + threadIdx.x;

    // [0] LR xyz (exact reference f32 op order: (i*vs + off) + 0.5*vs)
    if (e < BM) {
        int iz = lr_idx[e*3], iy = lr_idx[e*3+1], ix = lr_idx[e*3+2];
        float4 v;
        v.x = __fadd_rn(__fadd_rn(__fmul_rn((float)ix, 0.4f),   0.0f), __fmul_rn(0.5f, 0.4f));
        v.y = __fadd_rn(__fadd_rn(__fmul_rn((float)iy, 0.4f), -40.0f), __fmul_rn(0.5f, 0.4f));
        v.z = __fadd_rn(__fadd_rn(__fmul_rn((float)iz, 1.0f),  -3.0f), __fmul_rn(0.5f, 1.0f));
        v.w = 0.f;
        reinterpret_cast<float4*>(ws)[e] = v;
        return;
    }
    e -= BM;

    // [1] HR xyz for 3 sets
    if (e < 2*(NN1+NN2+NN3)) {
        const int* ip; float vsx, vsz; int off; int r = e;
        if (r < 2*NN1)                { ip = h1i; vsx = 0.05f; vsz = 0.1f; off = OFF_XYZ1; }
        else if ((r -= 2*NN1) < 2*NN2){ ip = h2i; vsx = 0.1f;  vsz = 0.2f; off = OFF_XYZ2; }
        else                          { r -= 2*NN2; ip = h3i; vsx = 0.2f; vsz = 0.4f; off = OFF_XYZ3; }
        int iz = ip[r*3], iy = ip[r*3+1], ix = ip[r*3+2];
        float4 v;
        v.x = __fadd_rn(__fadd_rn(__fmul_rn((float)ix, vsx),   0.0f), __fmul_rn(0.5f, vsx));
        v.y = __fadd_rn(__fadd_rn(__fmul_rn((float)iy, vsx), -40.0f), __fmul_rn(0.5f, vsx));
        v.z = __fadd_rn(__fadd_rn(__fmul_rn((float)iz, vsz),  -3.0f), __fmul_rn(0.5f, vsz));
        v.w = 0.f;
        reinterpret_cast<float4*>(ws + off)[r] = v;
        return;
    }
    e -= 2*(NN1+NN2+NN3);

    // [2..4] F_s[jj][o] = b_s[o] + sum_c feat[jj][c] * w_s[(3+c)*32+o]
    if (e < 2*NN1*32) {
        int o = e & 31, jj = e >> 5;
        float acc = b14[o];
        for (int c = 0; c < 16; ++c) acc = fmaf(f1[jj*16+c], w14[(3+c)*32+o], acc);
        ws[OFF_F1 + e] = acc;
        return;
    }
    e -= 2*NN1*32;
    if (e < 2*NN2*32) {
        int o = e & 31, jj = e >> 5;
        float acc = b24[o];
        for (int c = 0; c < 32; ++c) acc = fmaf(f2[jj*32+c], w24[(3+c)*32+o], acc);
        ws[OFF_F2 + e] = acc;
        return;
    }
    e -= 2*NN2*32;
    if (e < 2*NN3*32) {
        int o = e & 31, jj = e >> 5;
        float acc = b34[o];
        for (int c = 0; c < 64; ++c) acc = fmaf(f3[jj*64+c], w34[(3+c)*32+o], acc);
        ws[OFF_F3 + e] = acc;
        return;
    }
    e -= 2*NN3*32;

    // [5] BN-folded w' and shift
    if (e < 10240 + 64) {
        if (e < 10240) {
            int o = e & 63;
            float sc = gam[o] * (1.0f / sqrtf(var[o] + 1e-3f));
            ws[OFF_WP + e] = wout[e] * sc;
        } else {
            int o = e - 10240;
            float sc = gam[o] * (1.0f / sqrtf(var[o] + 1e-3f));
            ws[OFF_SHIFT + o] = bet[o] - mean[o] * sc;
        }
        return;
    }
    e -= 10304;

    // [6] zero acc + counters
    if (e < ZERO_LEN) {
        reinterpret_cast<int*>(ws)[ZERO_BASE + e] = 0;
    }
}

// ---------------- kernel B: ball-query scan + fused MLP + atomic max-pool ----------------
// Each lane owns one LR point; the wave steps through HR points (uniform address,
// HW-broadcast L2 hits). Hit => 32-ch MLP tail (3 FMA/ch) + relu-folded atomicMax.
__global__ __launch_bounds__(256) void kscan(
    float* __restrict__ ws,
    const float* __restrict__ w14, const float* __restrict__ w24, const float* __restrict__ w34)
{
    int lane = threadIdx.x & 63;
    int wid = __builtin_amdgcn_readfirstlane(blockIdx.x * 4 + (threadIdx.x >> 6));

    int pg, ck, N;
    const float* wS;
    int xyzoff, Foff, accoff, cntoff;
    if (wid < 4096) {          // set1: 128 pg x 32 chunks
        pg = wid >> 5; ck = wid & 31; N = NN1; wS = w14;
        xyzoff = OFF_XYZ1; Foff = OFF_F1; accoff = OFF_ACC1; cntoff = OFF_CNT1;
    } else if (wid < 6144) {   // set2: 128 pg x 16 chunks
        int w2 = wid - 4096;
        pg = w2 >> 4; ck = w2 & 15; N = NN2; wS = w24;
        xyzoff = OFF_XYZ2; Foff = OFF_F2; accoff = OFF_ACC2; cntoff = OFF_CNT2;
    } else {                   // set3: 128 pg x 8 chunks
        int w3 = wid - 6144;
        pg = w3 >> 3; ck = w3 & 7; N = NN3; wS = w34;
        xyzoff = OFF_XYZ3; Foff = OFF_F3; accoff = OFF_ACC3; cntoff = OFF_CNT3;
    }

    int b = pg >> 6;                 // wave-uniform batch
    int p = pg * 64 + lane;          // this lane's LR point
    float4 lr = reinterpret_cast<const float4*>(ws)[p];

    int jbase = ck * 512;
    const float4* xz = reinterpret_cast<const float4*>(ws + xyzoff) + (b * N + jbase);
    const float* F = ws + Foff + (size_t)(b * N) * 32;
    int* acc = reinterpret_cast<int*>(ws) + accoff + p * 32;
    int* cnt = reinterpret_cast<int*>(ws) + cntoff;

    int nhits = 0;
    #pragma unroll 2
    for (int t = 0; t < 512; ++t) {
        float4 q = xz[t];            // uniform address -> broadcast, L2-hot
        float dx = q.x - lr.x, dy = q.y - lr.y, dz = q.z - lr.z;
        // exact np op order: ((dx^2 + dy^2) + dz^2) < 1.0, no FMA contraction
        float d2 = __fadd_rn(__fadd_rn(__fmul_rn(dx, dx), __fmul_rn(dy, dy)), __fmul_rn(dz, dz));
        if (d2 < 1.0f) {
            ++nhits;
            const float* Fr = F + (size_t)(jbase + t) * 32;
            #pragma unroll
            for (int o4 = 0; o4 < 8; ++o4) {
                float4 f4  = reinterpret_cast<const float4*>(Fr)[o4];
                float4 wx4 = reinterpret_cast<const float4*>(wS)[o4];
                float4 wy4 = reinterpret_cast<const float4*>(wS + 32)[o4];
                float4 wz4 = reinterpret_cast<const float4*>(wS + 64)[o4];
                float h0 = f4.x + dx*wx4.x + dy*wy4.x + dz*wz4.x;
                float h1 = f4.y + dx*wx4.y + dy*wy4.y + dz*wz4.y;
                float h2 = f4.z + dx*wx4.z + dy*wy4.z + dz*wz4.z;
                float h3 = f4.w + dx*wx4.w + dy*wy4.w + dz*wz4.w;
                // relu+max-pool fold: init is 0, signed-int max never stores negatives
                atomicMax(acc + o4*4 + 0, __float_as_int(h0));
                atomicMax(acc + o4*4 + 1, __float_as_int(h1));
                atomicMax(acc + o4*4 + 2, __float_as_int(h2));
                atomicMax(acc + o4*4 + 3, __float_as_int(h3));
            }
        }
    }
    if (nhits) atomicAdd(cnt + p, nhits);
}

// ---------------- kernel C: fallback + concat + 160x64 matmul + BN + ReLU ----------------
__global__ __launch_bounds__(256) void kfinal(
    const float* __restrict__ ws, const float* __restrict__ lr_feat,
    const float* __restrict__ w14, const float* __restrict__ w24, const float* __restrict__ w34,
    float* __restrict__ out)
{
    __shared__ float cat_s[32][160];
    int wv = threadIdx.x >> 6, lane = threadIdx.x & 63;
    int p0 = blockIdx.x * 32 + wv * 8;   // this wave: 8 points

    #pragma unroll
    for (int pt = 0; pt < 8; ++pt)
        cat_s[wv*8 + pt][lane] = lr_feat[(p0 + pt) * 64 + lane];

    if (lane < 32) {
        int o = lane;
        for (int pt = 0; pt < 8; ++pt) {
            int p = p0 + pt; int b = p >> 12;
            float4 lr = reinterpret_cast<const float4*>(ws)[p];
            const int* wsi = reinterpret_cast<const int*>(ws);
            float f;
            // set1 (zero hits -> reference falls back to neighbor index 0)
            if (wsi[OFF_CNT1 + p] > 0) f = __int_as_float(wsi[OFF_ACC1 + p*32 + o]);
            else {
                float4 q = reinterpret_cast<const float4*>(ws + OFF_XYZ1)[b * NN1];
                float dx = q.x - lr.x, dy = q.y - lr.y, dz = q.z - lr.z;
                f = fmaxf(ws[OFF_F1 + (size_t)b*NN1*32 + o] + dx*w14[o] + dy*w14[32+o] + dz*w14[64+o], 0.f);
            }
            cat_s[wv*8 + pt][64 + o] = f;
            // set2
            if (wsi[OFF_CNT2 + p] > 0) f = __int_as_float(wsi[OFF_ACC2 + p*32 + o]);
            else {
                float4 q = reinterpret_cast<const float4*>(ws + OFF_XYZ2)[b * NN2];
                float dx = q.x - lr.x, dy = q.y - lr.y, dz = q.z - lr.z;
                f = fmaxf(ws[OFF_F2 + (size_t)b*NN2*32 + o] + dx*w24[o] + dy*w24[32+o] + dz*w24[64+o], 0.f);
            }
            cat_s[wv*8 + pt][96 + o] = f;
            // set3
            if (wsi[OFF_CNT3 + p] > 0) f = __int_as_float(wsi[OFF_ACC3 + p*32 + o]);
            else {
                float4 q = reinterpret_cast<const float4*>(ws + OFF_XYZ3)[b * NN3];
                float dx = q.x - lr.x, dy = q.y - lr.y, dz = q.z - lr.z;
                f = fmaxf(ws[OFF_F3 + (size_t)b*NN3*32 + o] + dx*w34[o] + dy*w34[32+o] + dz*w34[64+o], 0.f);
            }
            cat_s[wv*8 + pt][128 + o] = f;
        }
    }
    __syncthreads();

    float sh = ws[OFF_SHIFT + lane];
    float acc[8];
    #pragma unroll
    for (int pt = 0; pt < 8; ++pt) acc[pt] = sh;

    const float* wp = ws + OFF_WP;
    #pragma unroll 2
    for (int c = 0; c < 160; c += 4) {
        float w0 = wp[(c+0)*64 + lane];
        float w1 = wp[(c+1)*64 + lane];
        float w2 = wp[(c+2)*64 + lane];
        float w3 = wp[(c+3)*64 + lane];
        #pragma unroll
        for (int pt = 0; pt < 8; ++pt) {
            float4 cv = *reinterpret_cast<const float4*>(&cat_s[wv*8 + pt][c]);
            acc[pt] = fmaf(cv.x, w0, acc[pt]);
            acc[pt] = fmaf(cv.y, w1, acc[pt]);
            acc[pt] = fmaf(cv.z, w2, acc[pt]);
            acc[pt] = fmaf(cv.w, w3, acc[pt]);
        }
    }
    #pragma unroll
    for (int pt = 0; pt < 8; ++pt)
        out[(p0 + pt) * 64 + lane] = fmaxf(acc[pt], 0.f);
}

// ---------------- host launcher ----------------
extern "C" void kernel_launch(void* const* d_in, const int* in_sizes, int n_in,
                              void* d_out, int out_size, void* d_ws, size_t ws_size,
                              hipStream_t stream) {
    const int*   lr_idx = (const int*)d_in[0];
    const int*   h1i    = (const int*)d_in[1];
    const int*   h2i    = (const int*)d_in[2];
    const int*   h3i    = (const int*)d_in[3];
    const float* lrf    = (const float*)d_in[4];
    const float* f1     = (const float*)d_in[5];
    const float* f2     = (const float*)d_in[6];
    const float* f3     = (const float*)d_in[7];
    const float* w14    = (const float*)d_in[8];
    const float* b14    = (const float*)d_in[9];
    const float* w24    = (const float*)d_in[10];
    const float* b24    = (const float*)d_in[11];
    const float* w34    = (const float*)d_in[12];
    const float* b34    = (const float*)d_in[13];
    const float* wout   = (const float*)d_in[14];
    const float* gam    = (const float*)d_in[15];
    const float* bet    = (const float*)d_in[16];
    const float* mean   = (const float*)d_in[17];
    const float* var    = (const float*)d_in[18];
    float* ws  = (float*)d_ws;
    float* out = (float*)d_out;

    if (ws_size < (size_t)WS_FLOATS * sizeof(float)) return;  // need ~11.7 MB scratch

    // A: 8192 + 57344 + 1048576 + 524288 + 262144 + 10304 + 811008 = 2721856 threads
    kprep<<<10633, 256, 0, stream>>>(lr_idx, h1i, h2i, h3i, f1, f2, f3,
                                     w14, b14, w24, b24, w34, b34,
                                     wout, gam, bet, mean, var, ws);
    // B: 7168 waves = 128 point-groups x (32+16+8) chunks
    kscan<<<1792, 256, 0, stream>>>(ws, w14, w24, w34);
    // C: 256 blocks x 32 points
    kfinal<<<256, 256, 0, stream>>>(ws, lrf, w14, w24, w34, out);
}

// Round 4
// 318.514 us; speedup vs baseline: 1.1048x; 1.1048x over previous
//
#include <hip/hip_runtime.h>

// ---------------- problem constants ----------------
#define BM   8192      // B*M = 2*4096 points
#define NN1  16384
#define NN2  8192
#define NN3  4096
#define NB   80        // y bins (y in [-40,40), width 1.0)

// ---------------- workspace layout (float element offsets) ----------------
#define OFF_LRXYZ 0            // 8192 float4 (unsorted, w=0)
#define OFF_LRS   32768        // 8192 float4 (y-sorted per batch, w=orig p)
#define OFF_XYZ1  65536        // 2*16384 float4 unsorted
#define OFF_XYZ2  196608       // 2*8192
#define OFF_XYZ3  262144       // 2*4096
#define OFF_S1    294912       // sorted set1 (w = orig j within batch)
#define OFF_S2    425984
#define OFF_S3    491520
#define OFF_F1    524288       // 2*16384*32 f32 (orig-indexed)
#define OFF_F2    1572864
#define OFF_F3    2097152
#define OFF_ACC1  2359296      // 8192*32 int bits of relu'd f32
#define OFF_ACC2  2621440
#define OFF_ACC3  2883584
#define OFF_CNT1  3145728      // 8192 int
#define OFF_CNT2  3153920
#define OFF_CNT3  3162112
#define OFF_BINS  3170304      // int area, 2048 reserved
#define OFF_WP    3172352      // 160*64 BN-folded w_out
#define OFF_SHIFT 3182592      // 64
#define WS_FLOATS 3182656      // ~12.7 MB

#define ZERO_BASE OFF_ACC1
#define ZERO_LEN  813056       // acc1..bins end (ints), int4-zeroed

// bin-table sub-offsets (ints, relative to OFF_BINS)
//  HR starts : (s*2+b)*81 + k            [0,486)
//  HR cursor : 486 + (s*2+b)*80 + k      [486,966)
//  LR starts : 966 + b*81 + k            [966,1128)
//  LR cursor : 1128 + b*80 + k           [1128,1288)

// ---------------- kernel A: coords, F, w', zero ----------------
__global__ __launch_bounds__(256) void kprep(
    const int* __restrict__ lr_idx, const int* __restrict__ h1i,
    const int* __restrict__ h2i, const int* __restrict__ h3i,
    const float* __restrict__ f1, const float* __restrict__ f2, const float* __restrict__ f3,
    const float* __restrict__ w14, const float* __restrict__ b14,
    const float* __restrict__ w24, const float* __restrict__ b24,
    const float* __restrict__ w34, const float* __restrict__ b34,
    const float* __restrict__ wout, const float* __restrict__ gam,
    const float* __restrict__ bet, const float* __restrict__ mean,
    const float* __restrict__ var, float* __restrict__ ws)
{
    int e = blockIdx.x * 256 + threadIdx.x;

    // [0] LR xyz (exact reference f32 op order)
    if (e < BM) {
        int iz = lr_idx[e*3], iy = lr_idx[e*3+1], ix = lr_idx[e*3+2];
        float4 v;
        v.x = __fadd_rn(__fadd_rn(__fmul_rn((float)ix, 0.4f),   0.0f), __fmul_rn(0.5f, 0.4f));
        v.y = __fadd_rn(__fadd_rn(__fmul_rn((float)iy, 0.4f), -40.0f), __fmul_rn(0.5f, 0.4f));
        v.z = __fadd_rn(__fadd_rn(__fmul_rn((float)iz, 1.0f),  -3.0f), __fmul_rn(0.5f, 1.0f));
        v.w = 0.f;
        reinterpret_cast<float4*>(ws)[e] = v;
        return;
    }
    e -= BM;

    // [1] HR xyz
    if (e < 2*(NN1+NN2+NN3)) {
        const int* ip; float vsx, vsz; int off; int r = e;
        if (r < 2*NN1)                { ip = h1i; vsx = 0.05f; vsz = 0.1f; off = OFF_XYZ1; }
        else if ((r -= 2*NN1) < 2*NN2){ ip = h2i; vsx = 0.1f;  vsz = 0.2f; off = OFF_XYZ2; }
        else                          { r -= 2*NN2; ip = h3i; vsx = 0.2f; vsz = 0.4f; off = OFF_XYZ3; }
        int iz = ip[r*3], iy = ip[r*3+1], ix = ip[r*3+2];
        float4 v;
        v.x = __fadd_rn(__fadd_rn(__fmul_rn((float)ix, vsx),   0.0f), __fmul_rn(0.5f, vsx));
        v.y = __fadd_rn(__fadd_rn(__fmul_rn((float)iy, vsx), -40.0f), __fmul_rn(0.5f, vsx));
        v.z = __fadd_rn(__fadd_rn(__fmul_rn((float)iz, vsz),  -3.0f), __fmul_rn(0.5f, vsz));
        v.w = 0.f;
        reinterpret_cast<float4*>(ws + off)[r] = v;
        return;
    }
    e -= 2*(NN1+NN2+NN3);

    // [2..4] F_s[jj][o] = b_s[o] + sum_c feat[jj][c] * w_s[(3+c)*32+o]
    if (e < 2*NN1*32) {
        int o = e & 31, jj = e >> 5;
        const float4* fv = reinterpret_cast<const float4*>(f1) + jj*4;
        float acc = b14[o];
        #pragma unroll
        for (int c4 = 0; c4 < 4; ++c4) {
            float4 f = fv[c4];
            acc = fmaf(f.x, w14[(3+c4*4+0)*32+o], acc);
            acc = fmaf(f.y, w14[(3+c4*4+1)*32+o], acc);
            acc = fmaf(f.z, w14[(3+c4*4+2)*32+o], acc);
            acc = fmaf(f.w, w14[(3+c4*4+3)*32+o], acc);
        }
        ws[OFF_F1 + e] = acc;
        return;
    }
    e -= 2*NN1*32;
    if (e < 2*NN2*32) {
        int o = e & 31, jj = e >> 5;
        const float4* fv = reinterpret_cast<const float4*>(f2) + jj*8;
        float acc = b24[o];
        #pragma unroll
        for (int c4 = 0; c4 < 8; ++c4) {
            float4 f = fv[c4];
            acc = fmaf(f.x, w24[(3+c4*4+0)*32+o], acc);
            acc = fmaf(f.y, w24[(3+c4*4+1)*32+o], acc);
            acc = fmaf(f.z, w24[(3+c4*4+2)*32+o], acc);
            acc = fmaf(f.w, w24[(3+c4*4+3)*32+o], acc);
        }
        ws[OFF_F2 + e] = acc;
        return;
    }
    e -= 2*NN2*32;
    if (e < 2*NN3*32) {
        int o = e & 31, jj = e >> 5;
        const float4* fv = reinterpret_cast<const float4*>(f3) + jj*16;
        float acc = b34[o];
        #pragma unroll
        for (int c4 = 0; c4 < 16; ++c4) {
            float4 f = fv[c4];
            acc = fmaf(f.x, w34[(3+c4*4+0)*32+o], acc);
            acc = fmaf(f.y, w34[(3+c4*4+1)*32+o], acc);
            acc = fmaf(f.z, w34[(3+c4*4+2)*32+o], acc);
            acc = fmaf(f.w, w34[(3+c4*4+3)*32+o], acc);
        }
        ws[OFF_F3 + e] = acc;
        return;
    }
    e -= 2*NN3*32;

    // [5] BN-folded w' and shift
    if (e < 10240 + 64) {
        if (e < 10240) {
            int o = e & 63;
            float sc = gam[o] * (1.0f / sqrtf(var[o] + 1e-3f));
            ws[OFF_WP + e] = wout[e] * sc;
        } else {
            int o = e - 10240;
            float sc = gam[o] * (1.0f / sqrtf(var[o] + 1e-3f));
            ws[OFF_SHIFT + o] = bet[o] - mean[o] * sc;
        }
        return;
    }
    e -= 10304;

    // [6] zero acc + counters + bin tables (int4)
    if (e < ZERO_LEN/4) {
        reinterpret_cast<int4*>(reinterpret_cast<int*>(ws) + ZERO_BASE)[e] = make_int4(0,0,0,0);
    }
}

// ---------------- kernel B1: y-bin histogram ----------------
__global__ __launch_bounds__(256) void khist(float* __restrict__ ws)
{
    int e = blockIdx.x * 256 + threadIdx.x;
    int* base = reinterpret_cast<int*>(ws) + OFF_BINS;
    if (e < BM) {
        float y = ws[OFF_LRXYZ + e*4 + 1];
        int b = e >> 12;
        int k = min(NB-1, max(0, (int)floorf(y + 40.0f)));
        atomicAdd(base + 966 + b*81 + k, 1);
        return;
    }
    e -= BM;
    int s, N, off;
    if (e < 2*NN1)                 { s = 0; N = NN1; off = OFF_XYZ1; }
    else if ((e -= 2*NN1) < 2*NN2) { s = 1; N = NN2; off = OFF_XYZ2; }
    else                           { e -= 2*NN2; s = 2; N = NN3; off = OFF_XYZ3; }
    int b = (e >= N) ? 1 : 0;
    float y = ws[off + e*4 + 1];
    int k = min(NB-1, max(0, (int)floorf(y + 40.0f)));
    atomicAdd(base + (s*2+b)*81 + k, 1);
}

// ---------------- kernel B2: exclusive prefix + cursor init ----------------
__global__ void kprefix(float* __restrict__ ws)
{
    int t = threadIdx.x;
    int* base = reinterpret_cast<int*>(ws) + OFF_BINS;
    if (t < 8) {
        int *st, *cu;
        if (t < 6) { st = base + t*81;       cu = base + 486 + t*80; }
        else       { st = base + 966 + (t-6)*81; cu = base + 1128 + (t-6)*80; }
        int run = 0;
        for (int k = 0; k < NB; ++k) { int c = st[k]; st[k] = run; cu[k] = run; run += c; }
        st[NB] = run;
    }
}

// ---------------- kernel B3: scatter into sorted arrays (w = orig index) ----------------
__global__ __launch_bounds__(256) void kscatter(float* __restrict__ ws)
{
    int e = blockIdx.x * 256 + threadIdx.x;
    int* base = reinterpret_cast<int*>(ws) + OFF_BINS;
    if (e < BM) {
        float4 v = reinterpret_cast<const float4*>(ws + OFF_LRXYZ)[e];
        int b = e >> 12;
        int k = min(NB-1, max(0, (int)floorf(v.y + 40.0f)));
        int pos = atomicAdd(base + 1128 + b*80 + k, 1);
        v.w = __int_as_float(e);   // orig global p
        reinterpret_cast<float4*>(ws + OFF_LRS)[b*4096 + pos] = v;
        return;
    }
    e -= BM;
    int s, N, off, soff;
    if (e < 2*NN1)                 { s = 0; N = NN1; off = OFF_XYZ1; soff = OFF_S1; }
    else if ((e -= 2*NN1) < 2*NN2) { s = 1; N = NN2; off = OFF_XYZ2; soff = OFF_S2; }
    else                           { e -= 2*NN2; s = 2; N = NN3; off = OFF_XYZ3; soff = OFF_S3; }
    int b = (e >= N) ? 1 : 0;
    float4 v = reinterpret_cast<const float4*>(ws + off)[e];
    int k = min(NB-1, max(0, (int)floorf(v.y + 40.0f)));
    int pos = atomicAdd(base + 486 + (s*2+b)*80 + k, 1);
    v.w = __int_as_float(e - b*N);  // orig j within batch
    reinterpret_cast<float4*>(ws + soff)[b*N + pos] = v;
}

// ---------------- kernel C: pruned ball-query scan + fused MLP + atomic max-pool ----------------
// Wave = 64 y-adjacent sorted LR points; candidate set = contiguous sorted-HR
// interval covering [ymin-1, ymax+1]; split over chunk-waves for parallelism.
__global__ __launch_bounds__(256) void kscan(
    float* __restrict__ ws,
    const float* __restrict__ w14, const float* __restrict__ w24, const float* __restrict__ w34)
{
    int lane = threadIdx.x & 63;
    int wid = blockIdx.x * 4 + (threadIdx.x >> 6);

    int pg, ck, C, N, s;
    const float* wS;
    int soff, Foff, accoff, cntoff;
    if (wid < 2048) {          // set1: 128 lr-waves x 16 chunks
        s = 0; pg = wid >> 4; ck = wid & 15; C = 16; N = NN1; wS = w14;
        soff = OFF_S1; Foff = OFF_F1; accoff = OFF_ACC1; cntoff = OFF_CNT1;
    } else if (wid < 3072) {   // set2: x 8
        int w = wid - 2048;
        s = 1; pg = w >> 3; ck = w & 7; C = 8; N = NN2; wS = w24;
        soff = OFF_S2; Foff = OFF_F2; accoff = OFF_ACC2; cntoff = OFF_CNT2;
    } else {                   // set3: x 4
        int w = wid - 3072;
        s = 2; pg = w >> 2; ck = w & 3; C = 4; N = NN3; wS = w34;
        soff = OFF_S3; Foff = OFF_F3; accoff = OFF_ACC3; cntoff = OFF_CNT3;
    }

    int b = pg >> 6;   // 64 waves per batch
    float4 lr = reinterpret_cast<const float4*>(ws + OFF_LRS)[pg*64 + lane];
    int porig = __float_as_int(lr.w);

    // wave y-range (butterfly; identical in all lanes)
    float ymin = lr.y, ymax = lr.y;
    #pragma unroll
    for (int m = 1; m < 64; m <<= 1) {
        ymin = fminf(ymin, __shfl_xor(ymin, m));
        ymax = fmaxf(ymax, __shfl_xor(ymax, m));
    }
    int klo = max(0, (int)floorf(ymin - 1.001f + 40.0f));
    int khi = min(NB-1, (int)floorf(ymax + 1.001f + 40.0f));

    const int* st = reinterpret_cast<const int*>(ws) + OFF_BINS + (s*2+b)*81;
    int j0 = st[klo], j1 = st[khi+1];
    int len = j1 - j0;
    int ja = j0 + (len * ck) / C;
    int je = j0 + (len * (ck+1)) / C;

    const float4* S = reinterpret_cast<const float4*>(ws + soff) + b*N;
    const float* F = ws + Foff + (size_t)b*N*32;
    int* acc = reinterpret_cast<int*>(ws) + accoff + porig*32;
    int nhits = 0;

    #pragma unroll 4
    for (int j = ja; j < je; ++j) {
        float4 q = S[j];
        float dx = q.x - lr.x, dy = q.y - lr.y, dz = q.z - lr.z;
        // exact np op order: ((dx^2 + dy^2) + dz^2) < 1.0, no FMA contraction
        float d2 = __fadd_rn(__fadd_rn(__fmul_rn(dx, dx), __fmul_rn(dy, dy)), __fmul_rn(dz, dz));
        if (d2 < 1.0f) {
            ++nhits;
            int jorig = __float_as_int(q.w);
            const float* Fr = F + (size_t)jorig * 32;
            #pragma unroll
            for (int o4 = 0; o4 < 8; ++o4) {
                float4 f4  = reinterpret_cast<const float4*>(Fr)[o4];
                float4 wx4 = reinterpret_cast<const float4*>(wS)[o4];
                float4 wy4 = reinterpret_cast<const float4*>(wS + 32)[o4];
                float4 wz4 = reinterpret_cast<const float4*>(wS + 64)[o4];
                float h0 = f4.x + dx*wx4.x + dy*wy4.x + dz*wz4.x;
                float h1 = f4.y + dx*wx4.y + dy*wy4.y + dz*wz4.y;
                float h2 = f4.z + dx*wx4.z + dy*wy4.z + dz*wz4.z;
                float h3 = f4.w + dx*wx4.w + dy*wy4.w + dz*wz4.w;
                atomicMax(acc + o4*4 + 0, __float_as_int(h0));
                atomicMax(acc + o4*4 + 1, __float_as_int(h1));
                atomicMax(acc + o4*4 + 2, __float_as_int(h2));
                atomicMax(acc + o4*4 + 3, __float_as_int(h3));
            }
        }
    }
    if (nhits) atomicAdd(reinterpret_cast<int*>(ws) + cntoff + porig, nhits);
}

// ---------------- kernel D: fallback + concat + 160x64 matmul + BN + ReLU ----------------
__global__ __launch_bounds__(256) void kfinal(
    const float* __restrict__ ws, const float* __restrict__ lr_feat,
    const float* __restrict__ w14, const float* __restrict__ w24, const float* __restrict__ w34,
    float* __restrict__ out)
{
    __shared__ float cat_s[32][160];
    int wv = threadIdx.x >> 6, lane = threadIdx.x & 63;
    int p0 = blockIdx.x * 32 + wv * 8;   // this wave: 8 points

    #pragma unroll
    for (int pt = 0; pt < 8; ++pt)
        cat_s[wv*8 + pt][lane] = lr_feat[(p0 + pt) * 64 + lane];

    if (lane < 32) {
        int o = lane;
        for (int pt = 0; pt < 8; ++pt) {
            int p = p0 + pt; int b = p >> 12;
            float4 lr = reinterpret_cast<const float4*>(ws)[p];
            const int* wsi = reinterpret_cast<const int*>(ws);
            float f;
            // set1 (zero hits -> reference falls back to neighbor index 0)
            if (wsi[OFF_CNT1 + p] > 0) f = __int_as_float(wsi[OFF_ACC1 + p*32 + o]);
            else {
                float4 q = reinterpret_cast<const float4*>(ws + OFF_XYZ1)[b * NN1];
                float dx = q.x - lr.x, dy = q.y - lr.y, dz = q.z - lr.z;
                f = fmaxf(ws[OFF_F1 + (size_t)b*NN1*32 + o] + dx*w14[o] + dy*w14[32+o] + dz*w14[64+o], 0.f);
            }
            cat_s[wv*8 + pt][64 + o] = f;
            // set2
            if (wsi[OFF_CNT2 + p] > 0) f = __int_as_float(wsi[OFF_ACC2 + p*32 + o]);
            else {
                float4 q = reinterpret_cast<const float4*>(ws + OFF_XYZ2)[b * NN2];
                float dx = q.x - lr.x, dy = q.y - lr.y, dz = q.z - lr.z;
                f = fmaxf(ws[OFF_F2 + (size_t)b*NN2*32 + o] + dx*w24[o] + dy*w24[32+o] + dz*w24[64+o], 0.f);
            }
            cat_s[wv*8 + pt][96 + o] = f;
            // set3
            if (wsi[OFF_CNT3 + p] > 0) f = __int_as_float(wsi[OFF_ACC3 + p*32 + o]);
            else {
                float4 q = reinterpret_cast<const float4*>(ws + OFF_XYZ3)[b * NN3];
                float dx = q.x - lr.x, dy = q.y - lr.y, dz = q.z - lr.z;
                f = fmaxf(ws[OFF_F3 + (size_t)b*NN3*32 + o] + dx*w34[o] + dy*w34[32+o] + dz*w34[64+o], 0.f);
            }
            cat_s[wv*8 + pt][128 + o] = f;
        }
    }
    __syncthreads();

    float sh = ws[OFF_SHIFT + lane];
    float acc[8];
    #pragma unroll
    for (int pt = 0; pt < 8; ++pt) acc[pt] = sh;

    const float* wp = ws + OFF_WP;
    #pragma unroll 2
    for (int c = 0; c < 160; c += 4) {
        float w0 = wp[(c+0)*64 + lane];
        float w1 = wp[(c+1)*64 + lane];
        float w2 = wp[(c+2)*64 + lane];
        float w3 = wp[(c+3)*64 + lane];
        #pragma unroll
        for (int pt = 0; pt < 8; ++pt) {
            float4 cv = *reinterpret_cast<const float4*>(&cat_s[wv*8 + pt][c]);
            acc[pt] = fmaf(cv.x, w0, acc[pt]);
            acc[pt] = fmaf(cv.y, w1, acc[pt]);
            acc[pt] = fmaf(cv.z, w2, acc[pt]);
            acc[pt] = fmaf(cv.w, w3, acc[pt]);
        }
    }
    #pragma unroll
    for (int pt = 0; pt < 8; ++pt)
        out[(p0 + pt) * 64 + lane] = fmaxf(acc[pt], 0.f);
}

// ---------------- host launcher ----------------
extern "C" void kernel_launch(void* const* d_in, const int* in_sizes, int n_in,
                              void* d_out, int out_size, void* d_ws, size_t ws_size,
                              hipStream_t stream) {
    const int*   lr_idx = (const int*)d_in[0];
    const int*   h1i    = (const int*)d_in[1];
    const int*   h2i    = (const int*)d_in[2];
    const int*   h3i    = (const int*)d_in[3];
    const float* lrf    = (const float*)d_in[4];
    const float* f1     = (const float*)d_in[5];
    const float* f2     = (const float*)d_in[6];
    const float* f3     = (const float*)d_in[7];
    const float* w14    = (const float*)d_in[8];
    const float* b14    = (const float*)d_in[9];
    const float* w24    = (const float*)d_in[10];
    const float* b24    = (const float*)d_in[11];
    const float* w34    = (const float*)d_in[12];
    const float* b34    = (const float*)d_in[13];
    const float* wout   = (const float*)d_in[14];
    const float* gam    = (const float*)d_in[15];
    const float* bet    = (const float*)d_in[16];
    const float* mean   = (const float*)d_in[17];
    const float* var    = (const float*)d_in[18];
    float* ws  = (float*)d_ws;
    float* out = (float*)d_out;

    if (ws_size < (size_t)WS_FLOATS * sizeof(float)) return;  // need ~12.7 MB scratch

    // A: 8192+57344+1048576+524288+262144+10304+203264 = 2114112 threads
    kprep<<<8259, 256, 0, stream>>>(lr_idx, h1i, h2i, h3i, f1, f2, f3,
                                    w14, b14, w24, b24, w34, b34,
                                    wout, gam, bet, mean, var, ws);
    // sort by y-bin
    khist<<<256, 256, 0, stream>>>(ws);
    kprefix<<<1, 64, 0, stream>>>(ws);
    kscatter<<<256, 256, 0, stream>>>(ws);
    // pruned scan: 3584 waves = 128 lr-waves x (16+8+4) chunks
    kscan<<<896, 256, 0, stream>>>(ws, w14, w24, w34);
    // final: 256 blocks x 32 points
    kfinal<<<256, 256, 0, stream>>>(ws, lrf, w14, w24, w34, out);
}

// Round 6
// 186.286 us; speedup vs baseline: 1.8889x; 1.7098x over previous
//
#include <hip/hip_runtime.h>

// ---------------- problem constants ----------------
#define BM   8192      // B*M
#define NN1  16384
#define NN2  8192
#define NN3  4096
#define NB   80        // y bins, width 1.0, y+40 in [0,80)
#define NBLK 32        // sort blocks
#define ITEMS 65536    // 8192 LR + 2*(16384+8192+4096) HR
#define CHUNK 2048     // ITEMS/NBLK

// ---------------- workspace layout (float element offsets) ----------------
#define OFF_LRXYZ 0            // 8192 float4, orig order (kfinal)
#define OFF_LRS   32768        // 8192 float4 y-sorted, w=orig p
#define OFF_S1    65536        // sorted HR1, w=orig j in batch
#define OFF_S2    196608
#define OFF_S3    262144
#define OFF_F1    294912       // 2*16384*32 f32, orig-indexed
#define OFF_F2    1343488
#define OFF_F3    1867776
#define OFF_ACC1  2129920      // 8192*32 f32-bits (written by kscan stores)
#define OFF_ACC2  2392064
#define OFF_ACC3  2654208
#define OFF_CNT1  2916352      // 8192 int
#define OFF_CNT2  2924544
#define OFF_CNT3  2932736
#define OFF_PART  2940928      // int[NBLK*640] per-block histograms
#define OFF_BASE  2961408      // int[NBLK*640] per-block scatter bases
#define OFF_START 2981888      // int[648] = 8 tables x 81
#define OFF_WP    2982912      // 160*64 BN-folded w_out
#define OFF_SHIFT 2993152      // 64
#define WS_FLOATS 2993216      // ~12.0 MB

// table ids: HR s*2+b -> 0..5 ; LR 6+b

// ---------------- kernel A: LR xyz, F precompute, folded BN weights ----------------
__global__ __launch_bounds__(256) void kprep(
    const int* __restrict__ lr_idx,
    const float* __restrict__ f1, const float* __restrict__ f2, const float* __restrict__ f3,
    const float* __restrict__ w14, const float* __restrict__ b14,
    const float* __restrict__ w24, const float* __restrict__ b24,
    const float* __restrict__ w34, const float* __restrict__ b34,
    const float* __restrict__ wout, const float* __restrict__ gam,
    const float* __restrict__ bet, const float* __restrict__ mean,
    const float* __restrict__ var, float* __restrict__ ws)
{
    int e = blockIdx.x * 256 + threadIdx.x;

    // [0] LR xyz in original order (exact reference f32 op order)
    if (e < BM) {
        int iz = lr_idx[e*3], iy = lr_idx[e*3+1], ix = lr_idx[e*3+2];
        float4 v;
        v.x = __fadd_rn(__fadd_rn(__fmul_rn((float)ix, 0.4f),   0.0f), __fmul_rn(0.5f, 0.4f));
        v.y = __fadd_rn(__fadd_rn(__fmul_rn((float)iy, 0.4f), -40.0f), __fmul_rn(0.5f, 0.4f));
        v.z = __fadd_rn(__fadd_rn(__fmul_rn((float)iz, 1.0f),  -3.0f), __fmul_rn(0.5f, 1.0f));
        v.w = 0.f;
        reinterpret_cast<float4*>(ws)[e] = v;
        return;
    }
    e -= BM;

    // [1..3] F_s[jj][o] = b_s[o] + sum_c feat[jj][c] * w_s[(3+c)*32+o]
    if (e < 2*NN1*32) {
        int o = e & 31, jj = e >> 5;
        const float4* fv = reinterpret_cast<const float4*>(f1) + jj*4;
        float acc = b14[o];
        #pragma unroll
        for (int c4 = 0; c4 < 4; ++c4) {
            float4 f = fv[c4];
            acc = fmaf(f.x, w14[(3+c4*4+0)*32+o], acc);
            acc = fmaf(f.y, w14[(3+c4*4+1)*32+o], acc);
            acc = fmaf(f.z, w14[(3+c4*4+2)*32+o], acc);
            acc = fmaf(f.w, w14[(3+c4*4+3)*32+o], acc);
        }
        ws[OFF_F1 + e] = acc;
        return;
    }
    e -= 2*NN1*32;
    if (e < 2*NN2*32) {
        int o = e & 31, jj = e >> 5;
        const float4* fv = reinterpret_cast<const float4*>(f2) + jj*8;
        float acc = b24[o];
        #pragma unroll
        for (int c4 = 0; c4 < 8; ++c4) {
            float4 f = fv[c4];
            acc = fmaf(f.x, w24[(3+c4*4+0)*32+o], acc);
            acc = fmaf(f.y, w24[(3+c4*4+1)*32+o], acc);
            acc = fmaf(f.z, w24[(3+c4*4+2)*32+o], acc);
            acc = fmaf(f.w, w24[(3+c4*4+3)*32+o], acc);
        }
        ws[OFF_F2 + e] = acc;
        return;
    }
    e -= 2*NN2*32;
    if (e < 2*NN3*32) {
        int o = e & 31, jj = e >> 5;
        const float4* fv = reinterpret_cast<const float4*>(f3) + jj*16;
        float acc = b34[o];
        #pragma unroll
        for (int c4 = 0; c4 < 16; ++c4) {
            float4 f = fv[c4];
            acc = fmaf(f.x, w34[(3+c4*4+0)*32+o], acc);
            acc = fmaf(f.y, w34[(3+c4*4+1)*32+o], acc);
            acc = fmaf(f.z, w34[(3+c4*4+2)*32+o], acc);
            acc = fmaf(f.w, w34[(3+c4*4+3)*32+o], acc);
        }
        ws[OFF_F3 + e] = acc;
        return;
    }
    e -= 2*NN3*32;

    // [4] BN-folded w' and shift
    if (e < 10240 + 64) {
        if (e < 10240) {
            int o = e & 63;
            float sc = gam[o] * (1.0f / sqrtf(var[o] + 1e-3f));
            ws[OFF_WP + e] = wout[e] * sc;
        } else {
            int o = e - 10240;
            float sc = gam[o] * (1.0f / sqrtf(var[o] + 1e-3f));
            ws[OFF_SHIFT + o] = bet[o] - mean[o] * sc;
        }
    }
}

// ---------------- sort pass 1: per-block LDS histograms (no global atomics) ----------------
__global__ __launch_bounds__(1024) void khist1(
    const int* __restrict__ lr_idx, const int* __restrict__ h1i,
    const int* __restrict__ h2i, const int* __restrict__ h3i,
    float* __restrict__ ws)
{
    __shared__ int hist[640];
    int tid = threadIdx.x, bx = blockIdx.x;
    if (tid < 640) hist[tid] = 0;
    __syncthreads();
    int base_it = bx * CHUNK;
    for (int t = tid; t < CHUNK; t += 1024) {
        int e = base_it + t;
        int T, iy; float vsx;
        if (e < 8192)            { T = 6 + (e>>12); iy = lr_idx[e*3+1]; vsx = 0.4f; }
        else { int r = e - 8192;
          if (r < 32768)         { int b = r>>14; T = b;   iy = h1i[r*3+1]; vsx = 0.05f; }
          else { r -= 32768;
            if (r < 16384)       { int b = r>>13; T = 2+b; iy = h2i[r*3+1]; vsx = 0.1f; }
            else { r -= 16384; int b = r>>12; T = 4+b; iy = h3i[r*3+1]; vsx = 0.2f; }
          }
        }
        float y = __fadd_rn(__fadd_rn(__fmul_rn((float)iy, vsx), -40.0f), __fmul_rn(0.5f, vsx));
        int k = min(NB-1, max(0, (int)floorf(y + 40.0f)));
        atomicAdd(&hist[T*80 + k], 1);   // LDS atomic only
    }
    __syncthreads();
    if (tid < 640) reinterpret_cast<int*>(ws)[OFF_PART + bx*640 + tid] = hist[tid];
}

// ---------------- sort pass 2: totals, per-table prefix, per-block bases ----------------
__global__ __launch_bounds__(1024) void khist2(float* __restrict__ ws)
{
    __shared__ int tot[640];
    __shared__ int stt[648];
    int tid = threadIdx.x;
    int* parti = reinterpret_cast<int*>(ws) + OFF_PART;
    if (tid < 640) {
        int sm = 0;
        for (int b = 0; b < NBLK; ++b) sm += parti[b*640 + tid];
        tot[tid] = sm;
    }
    __syncthreads();
    if (tid < 8) {
        int run = 0;
        for (int k = 0; k < NB; ++k) { stt[tid*81 + k] = run; run += tot[tid*80 + k]; }
        stt[tid*81 + 80] = run;
    }
    __syncthreads();
    if (tid < 648) reinterpret_cast<int*>(ws)[OFF_START + tid] = stt[tid];
    if (tid < 640) {
        int run = stt[(tid/80)*81 + (tid%80)];
        int* baseG = reinterpret_cast<int*>(ws) + OFF_BASE;
        for (int b = 0; b < NBLK; ++b) { baseG[b*640 + tid] = run; run += parti[b*640 + tid]; }
    }
}

// ---------------- sort pass 3: scatter with LDS cursors (no global atomics) ----------------
__global__ __launch_bounds__(1024) void kscatter(
    const int* __restrict__ lr_idx, const int* __restrict__ h1i,
    const int* __restrict__ h2i, const int* __restrict__ h3i,
    float* __restrict__ ws)
{
    __shared__ int cur[640];
    int tid = threadIdx.x, bx = blockIdx.x;
    if (tid < 640) cur[tid] = reinterpret_cast<int*>(ws)[OFF_BASE + bx*640 + tid];
    __syncthreads();
    int base_it = bx * CHUNK;
    for (int t = tid; t < CHUNK; t += 1024) {
        int e = base_it + t;
        int T, w, dst4, r3; const int* ip; float vsx, vsz;
        if (e < 8192) {
            int b = e >> 12; T = 6+b; ip = lr_idx; r3 = e*3; vsx = 0.4f; vsz = 1.0f;
            w = e; dst4 = OFF_LRS/4 + b*4096;
        } else { int r = e - 8192;
          if (r < 32768) { int b = r>>14; T = b;   ip = h1i; r3 = r*3; vsx = 0.05f; vsz = 0.1f; w = r - b*NN1; dst4 = OFF_S1/4 + b*NN1; }
          else { r -= 32768;
            if (r < 16384) { int b = r>>13; T = 2+b; ip = h2i; r3 = r*3; vsx = 0.1f; vsz = 0.2f; w = r - b*NN2; dst4 = OFF_S2/4 + b*NN2; }
            else { r -= 16384; int b = r>>12; T = 4+b; ip = h3i; r3 = r*3; vsx = 0.2f; vsz = 0.4f; w = r - b*NN3; dst4 = OFF_S3/4 + b*NN3; }
          }
        }
        int iz = ip[r3], iy = ip[r3+1], ix = ip[r3+2];
        float4 v;
        v.x = __fadd_rn(__fadd_rn(__fmul_rn((float)ix, vsx),   0.0f), __fmul_rn(0.5f, vsx));
        v.y = __fadd_rn(__fadd_rn(__fmul_rn((float)iy, vsx), -40.0f), __fmul_rn(0.5f, vsx));
        v.z = __fadd_rn(__fadd_rn(__fmul_rn((float)iz, vsz),  -3.0f), __fmul_rn(0.5f, vsz));
        v.w = __int_as_float(w);
        int k = min(NB-1, max(0, (int)floorf(v.y + 40.0f)));
        int pos = atomicAdd(&cur[T*80 + k], 1);   // LDS atomic only
        reinterpret_cast<float4*>(ws)[dst4 + pos] = v;
    }
}

// ---------------- kernel C: pruned scan, LDS max-pool, plain stores ----------------
// One block (16 waves) per 64-point group per set. Chunk-waves ds_max into a
// shared accumulator; one coalesced global store at the end. No global atomics.
__global__ __launch_bounds__(1024) void kscan(
    float* __restrict__ ws,
    const float* __restrict__ w14, const float* __restrict__ w24, const float* __restrict__ w34)
{
    __shared__ int accS[64*33];   // pad 33: lane*33+o hits distinct banks
    __shared__ int cntS[64];
    __shared__ int porigS[64];

    int bx = blockIdx.x;
    int s = bx >> 7, pg = bx & 127;
    const float* wS; int soff, Foff, accoff, cntoff, N;
    if (s == 0)      { wS = w14; soff = OFF_S1; Foff = OFF_F1; accoff = OFF_ACC1; cntoff = OFF_CNT1; N = NN1; }
    else if (s == 1) { wS = w24; soff = OFF_S2; Foff = OFF_F2; accoff = OFF_ACC2; cntoff = OFF_CNT2; N = NN2; }
    else             { wS = w34; soff = OFF_S3; Foff = OFF_F3; accoff = OFF_ACC3; cntoff = OFF_CNT3; N = NN3; }

    int tid = threadIdx.x, lane = tid & 63, wv = tid >> 6;
    for (int e = tid; e < 64*33; e += 1024) accS[e] = 0;
    if (tid < 64) {
        cntS[tid] = 0;
        porigS[tid] = __float_as_int(reinterpret_cast<const float4*>(ws + OFF_LRS)[pg*64 + tid].w);
    }

    int b = pg >> 6;
    float4 lr = reinterpret_cast<const float4*>(ws + OFF_LRS)[pg*64 + lane];

    float ymin = lr.y, ymax = lr.y;
    #pragma unroll
    for (int m = 1; m < 64; m <<= 1) {
        ymin = fminf(ymin, __shfl_xor(ymin, m));
        ymax = fmaxf(ymax, __shfl_xor(ymax, m));
    }
    int klo = max(0, (int)floorf(ymin - 1.001f + 40.0f));
    int khi = min(NB-1, (int)floorf(ymax + 1.001f + 40.0f));
    const int* st = reinterpret_cast<const int*>(ws) + OFF_START + (s*2+b)*81;
    int j0 = st[klo], j1 = st[khi+1];
    int len = j1 - j0;
    int ja = j0 + (len * wv) / 16;
    int je = j0 + (len * (wv+1)) / 16;

    const float4* S = reinterpret_cast<const float4*>(ws + soff) + b*N;
    const float* F = ws + Foff + (size_t)b*N*32;
    int* accL = accS + lane*33;

    __syncthreads();

    int nhits = 0;
    #pragma unroll 4
    for (int j = ja; j < je; ++j) {
        float4 q = S[j];
        float dx = q.x - lr.x, dy = q.y - lr.y, dz = q.z - lr.z;
        // exact np op order, no FMA contraction
        float d2 = __fadd_rn(__fadd_rn(__fmul_rn(dx,dx), __fmul_rn(dy,dy)), __fmul_rn(dz,dz));
        if (d2 < 1.0f) {
            ++nhits;
            const float* Fr = F + (size_t)__float_as_int(q.w) * 32;
            #pragma unroll
            for (int o4 = 0; o4 < 8; ++o4) {
                float4 f4  = reinterpret_cast<const float4*>(Fr)[o4];
                float4 wx4 = reinterpret_cast<const float4*>(wS)[o4];
                float4 wy4 = reinterpret_cast<const float4*>(wS + 32)[o4];
                float4 wz4 = reinterpret_cast<const float4*>(wS + 64)[o4];
                atomicMax(accL + o4*4+0, __float_as_int(f4.x + dx*wx4.x + dy*wy4.x + dz*wz4.x));
                atomicMax(accL + o4*4+1, __float_as_int(f4.y + dx*wx4.y + dy*wy4.y + dz*wz4.y));
                atomicMax(accL + o4*4+2, __float_as_int(f4.z + dx*wx4.z + dy*wy4.z + dz*wz4.z));
                atomicMax(accL + o4*4+3, __float_as_int(f4.w + dx*wx4.w + dy*wy4.w + dz*wz4.w));
            }
        }
    }
    if (nhits) atomicAdd(&cntS[lane], nhits);
    __syncthreads();

    int* accG = reinterpret_cast<int*>(ws) + accoff;
    for (int e = tid; e < 2048; e += 1024) {
        int i = e >> 5, o = e & 31;
        accG[porigS[i]*32 + o] = accS[i*33 + o];
    }
    if (tid < 64) reinterpret_cast<int*>(ws)[cntoff + porigS[tid]] = cntS[tid];
}

// ---------------- kernel D: fallback + concat + 160x64 matmul + BN + ReLU ----------------
__global__ __launch_bounds__(256) void kfinal(
    const float* __restrict__ ws, const float* __restrict__ lr_feat,
    const int* __restrict__ h1i, const int* __restrict__ h2i, const int* __restrict__ h3i,
    const float* __restrict__ w14, const float* __restrict__ w24, const float* __restrict__ w34,
    float* __restrict__ out)
{
    __shared__ float cat_s[32][160];
    int wv = threadIdx.x >> 6, lane = threadIdx.x & 63;
    int p0 = blockIdx.x * 32 + wv * 8;

    #pragma unroll
    for (int pt = 0; pt < 8; ++pt)
        cat_s[wv*8 + pt][lane] = lr_feat[(p0 + pt) * 64 + lane];

    if (lane < 32) {
        int o = lane;
        for (int pt = 0; pt < 8; ++pt) {
            int p = p0 + pt; int b = p >> 12;
            float4 lr = reinterpret_cast<const float4*>(ws)[p];
            const int* wsi = reinterpret_cast<const int*>(ws);
            float f;
            // set1 (zero hits -> reference falls back to neighbor index 0)
            if (wsi[OFF_CNT1 + p] > 0) f = __int_as_float(wsi[OFF_ACC1 + p*32 + o]);
            else {
                int j3 = b*NN1*3;
                int hz = h1i[j3], hy = h1i[j3+1], hx = h1i[j3+2];
                float qx = __fadd_rn(__fadd_rn(__fmul_rn((float)hx, 0.05f),   0.0f), __fmul_rn(0.5f, 0.05f));
                float qy = __fadd_rn(__fadd_rn(__fmul_rn((float)hy, 0.05f), -40.0f), __fmul_rn(0.5f, 0.05f));
                float qz = __fadd_rn(__fadd_rn(__fmul_rn((float)hz, 0.1f),   -3.0f), __fmul_rn(0.5f, 0.1f));
                float dx = qx - lr.x, dy = qy - lr.y, dz = qz - lr.z;
                f = fmaxf(ws[OFF_F1 + (size_t)b*NN1*32 + o] + dx*w14[o] + dy*w14[32+o] + dz*w14[64+o], 0.f);
            }
            cat_s[wv*8 + pt][64 + o] = f;
            // set2
            if (wsi[OFF_CNT2 + p] > 0) f = __int_as_float(wsi[OFF_ACC2 + p*32 + o]);
            else {
                int j3 = b*NN2*3;
                int hz = h2i[j3], hy = h2i[j3+1], hx = h2i[j3+2];
                float qx = __fadd_rn(__fadd_rn(__fmul_rn((float)hx, 0.1f),   0.0f), __fmul_rn(0.5f, 0.1f));
                float qy = __fadd_rn(__fadd_rn(__fmul_rn((float)hy, 0.1f), -40.0f), __fmul_rn(0.5f, 0.1f));
                float qz = __fadd_rn(__fadd_rn(__fmul_rn((float)hz, 0.2f),  -3.0f), __fmul_rn(0.5f, 0.2f));
                float dx = qx - lr.x, dy = qy - lr.y, dz = qz - lr.z;
                f = fmaxf(ws[OFF_F2 + (size_t)b*NN2*32 + o] + dx*w24[o] + dy*w24[32+o] + dz*w24[64+o], 0.f);
            }
            cat_s[wv*8 + pt][96 + o] = f;
            // set3
            if (wsi[OFF_CNT3 + p] > 0) f = __int_as_float(wsi[OFF_ACC3 + p*32 + o]);
            else {
                int j3 = b*NN3*3;
                int hz = h3i[j3], hy = h3i[j3+1], hx = h3i[j3+2];
                float qx = __fadd_rn(__fadd_rn(__fmul_rn((float)hx, 0.2f),   0.0f), __fmul_rn(0.5f, 0.2f));
                float qy = __fadd_rn(__fadd_rn(__fmul_rn((float)hy, 0.2f), -40.0f), __fmul_rn(0.5f, 0.2f));
                float qz = __fadd_rn(__fadd_rn(__fmul_rn((float)hz, 0.4f),  -3.0f), __fmul_rn(0.5f, 0.4f));
                float dx = qx - lr.x, dy = qy - lr.y, dz = qz - lr.z;
                f = fmaxf(ws[OFF_F3 + (size_t)b*NN3*32 + o] + dx*w34[o] + dy*w34[32+o] + dz*w34[64+o], 0.f);
            }
            cat_s[wv*8 + pt][128 + o] = f;
        }
    }
    __syncthreads();

    float sh = ws[OFF_SHIFT + lane];
    float acc[8];
    #pragma unroll
    for (int pt = 0; pt < 8; ++pt) acc[pt] = sh;

    const float* wp = ws + OFF_WP;
    #pragma unroll 2
    for (int c = 0; c < 160; c += 4) {
        float w0 = wp[(c+0)*64 + lane];
        float w1 = wp[(c+1)*64 + lane];
        float w2 = wp[(c+2)*64 + lane];
        float w3 = wp[(c+3)*64 + lane];
        #pragma unroll
        for (int pt = 0; pt < 8; ++pt) {
            float4 cv = *reinterpret_cast<const float4*>(&cat_s[wv*8 + pt][c]);
            acc[pt] = fmaf(cv.x, w0, acc[pt]);
            acc[pt] = fmaf(cv.y, w1, acc[pt]);
            acc[pt] = fmaf(cv.z, w2, acc[pt]);
            acc[pt] = fmaf(cv.w, w3, acc[pt]);
        }
    }
    #pragma unroll
    for (int pt = 0; pt < 8; ++pt)
        out[(p0 + pt) * 64 + lane] = fmaxf(acc[pt], 0.f);
}

// ---------------- host launcher ----------------
extern "C" void kernel_launch(void* const* d_in, const int* in_sizes, int n_in,
                              void* d_out, int out_size, void* d_ws, size_t ws_size,
                              hipStream_t stream) {
    const int*   lr_idx = (const int*)d_in[0];
    const int*   h1i    = (const int*)d_in[1];
    const int*   h2i    = (const int*)d_in[2];
    const int*   h3i    = (const int*)d_in[3];
    const float* lrf    = (const float*)d_in[4];
    const float* f1     = (const float*)d_in[5];
    const float* f2     = (const float*)d_in[6];
    const float* f3     = (const float*)d_in[7];
    const float* w14    = (const float*)d_in[8];
    const float* b14    = (const float*)d_in[9];
    const float* w24    = (const float*)d_in[10];
    const float* b24    = (const float*)d_in[11];
    const float* w34    = (const float*)d_in[12];
    const float* b34    = (const float*)d_in[13];
    const float* wout   = (const float*)d_in[14];
    const float* gam    = (const float*)d_in[15];
    const float* bet    = (const float*)d_in[16];
    const float* mean   = (const float*)d_in[17];
    const float* var    = (const float*)d_in[18];
    float* ws  = (float*)d_ws;
    float* out = (float*)d_out;

    if (ws_size < (size_t)WS_FLOATS * sizeof(float)) return;  // ~12.0 MB scratch

    // A: 8192 + 1048576 + 524288 + 262144 + 10304 = 1853504 threads
    kprep<<<7241, 256, 0, stream>>>(lr_idx, f1, f2, f3,
                                    w14, b14, w24, b24, w34, b34,
                                    wout, gam, bet, mean, var, ws);
    // counting sort by y-bin, atomic-free at global scope
    khist1<<<NBLK, 1024, 0, stream>>>(lr_idx, h1i, h2i, h3i, ws);
    khist2<<<1, 1024, 0, stream>>>(ws);
    kscatter<<<NBLK, 1024, 0, stream>>>(lr_idx, h1i, h2i, h3i, ws);
    // pruned scan: 384 blocks (3 sets x 128 point-groups) x 16 waves
    kscan<<<384, 1024, 0, stream>>>(ws, w14, w24, w34);
    // final: 256 blocks x 32 points
    kfinal<<<256, 256, 0, stream>>>(ws, lrf, h1i, h2i, h3i, w14, w24, w34, out);
}